// Round 3
// baseline (552.854 us; speedup 1.0000x reference)
//
#include <hip/hip_runtime.h>
#include <math.h>

#define D 256
#define TBROWS 32768
#define BATCH 8
#define BM 32
#define KB 64

// workspace layout (float offsets) — total 559 KB
#define WS_M    0         // M[256][256] as float2 (re,im)  -> 131072 floats
#define WS_OD   131072    // op_decay[256] float2           -> 512
#define WS_C1   131584    // C1[8][256] float2 (gate*of)    -> 4096
#define WS_C0   135680    // C0[8][256] float2 (src*(1-g)*of)-> 4096

__device__ __forceinline__ float sigmoidf_(float x){ return 1.0f/(1.0f+expf(-x)); }

// ---- prep_batch: flux update + proj/gate + per-(b,d) epilogue coefficients ----
__global__ void prep_batch_kernel(const float* __restrict__ xg_re, const float* __restrict__ xg_im,
                                  const float* __restrict__ flux_re, const float* __restrict__ flux_im,
                                  const float* __restrict__ Wm, const float* __restrict__ bm,
                                  const float* __restrict__ decay_re, const float* __restrict__ decay_im,
                                  const float* __restrict__ Wp, const float* __restrict__ bp,
                                  const float* __restrict__ Wg, const float* __restrict__ bg,
                                  const float* __restrict__ lam_re, const float* __restrict__ lam_im,
                                  const int* __restrict__ dt_p,
                                  float* __restrict__ ws, float* __restrict__ out_flux, int cplx){
  __shared__ float vin[512];    // xg_cat, then s_cat
  __shared__ float mid[768];    // x_in, then {proj, gate_pre}
  const int b = blockIdx.x, j = threadIdx.x;
  if (j < 512) vin[j] = (j < D) ? xg_re[b*D + j] : xg_im[b*D + (j - D)];
  __syncthreads();
  if (j < 512){   // x_in = xg_cat @ Wm^T + bm
    const float4* row4 = (const float4*)(Wm + j*512);
    const float4* x4p  = (const float4*)vin;
    float acc = 0.f;
    #pragma unroll 8
    for (int k = 0; k < 128; ++k){
      float4 w4 = row4[k]; float4 x4 = x4p[k];
      acc += w4.x*x4.x + w4.y*x4.y + w4.z*x4.z + w4.w*x4.w;
    }
    mid[j] = acc + bm[j];
  }
  __syncthreads();
  if (j < D){     // flux_next = flux*fdecay + update
    float ur = mid[j], ui = mid[D + j];
    float fdr = sigmoidf_(decay_re[j]);
    float fdi = decay_im[j];
    float fr = flux_re[b*D + j], fi = flux_im[b*D + j];
    float nr = fr*fdr - fi*fdi + ur;
    float ni = fr*fdi + fi*fdr + ui;
    vin[j]     = nr;
    vin[D + j] = ni;
    if (cplx){ out_flux[(b*D + j)*2] = nr; out_flux[(b*D + j)*2 + 1] = ni; }
    else     { out_flux[b*D + j] = nr; }
  }
  __syncthreads();
  {               // proj (j<512) / gate_pre (j>=512)
    const float* rowp = (j < 512) ? (Wp + j*512) : (Wg + (j - 512)*512);
    float bias = (j < 512) ? bp[j] : bg[j - 512];
    const float4* row4 = (const float4*)rowp;
    const float4* x4p  = (const float4*)vin;
    float acc = 0.f;
    #pragma unroll 8
    for (int k = 0; k < 128; ++k){
      float4 w4 = row4[k]; float4 x4 = x4p[k];
      acc += w4.x*x4.x + w4.y*x4.y + w4.z*x4.z + w4.w*x4.w;
    }
    mid[j] = acc + bias;
  }
  __syncthreads();
  if (j < D){     // epilogue coefficients
    float sr = mid[j], si = mid[D + j];
    float g = sigmoidf_(mid[512 + j]);
    g = fminf(fmaxf(g, 0.01f), 0.99f);
    float lrb = fminf(fmaxf(lam_re[j], -0.3f), 0.3f);
    float li  = lam_im[j];
    float dtr = (float)dt_p[0];           // / DT_REF (=1.0)
    float er  = expf(lrb * dtr);
    float ang = li * dtr;
    float odr = er * cosf(ang), odi = er * sinf(ang);
    float sarg = lrb + 1e-12f;
    float sgn = (sarg > 0.f) ? 1.f : ((sarg < 0.f) ? -1.f : 0.f);
    float lrs = lrb + 1e-8f * sgn;
    float nr = odr - 1.f, ni = odi;
    float den = lrs*lrs + li*li;
    float ofr = (nr*lrs + ni*li) / den;
    float ofi = (ni*lrs - nr*li) / den;
    ws[WS_C1 + (b*D + j)*2]     = g * ofr;
    ws[WS_C1 + (b*D + j)*2 + 1] = g * ofi;
    float s1r = sr*(1.f - g), s1i = si*(1.f - g);
    ws[WS_C0 + (b*D + j)*2]     = s1r*ofr - s1i*ofi;
    ws[WS_C0 + (b*D + j)*2 + 1] = s1r*ofi + s1i*ofr;
    if (b == 0){
      ws[WS_OD + j*2]     = odr;
      ws[WS_OD + j*2 + 1] = odi;
    }
  }
}

// ---- prep_M: M = (1-w)*U + w*dft ----
__global__ void prep_M_kernel(const float* __restrict__ U_re, const float* __restrict__ U_im,
                              const float* __restrict__ dft_w, float* __restrict__ ws){
  const int k = blockIdx.x, n = threadIdx.x;
  float w = sigmoidf_(dft_w[0]);
  const float c = (float)(-6.283185307179586);
  // replicate reference op order: ((-2pi * col) * row) / 256
  float t1 = c * (float)n;
  float ph = (t1 * (float)k) / 256.0f;
  float dre = cosf(ph) * 0.0625f;   // / sqrt(256)
  float dim = sinf(ph) * 0.0625f;
  float mr = (1.f - w)*U_re[k*D + n] + w*dre;
  float mi = (1.f - w)*U_im[k*D + n] + w*dim;
  ws[WS_M + (k*D + n)*2]     = mr;
  ws[WS_M + (k*D + n)*2 + 1] = mi;
}

// ---- main: x_tilde = x @ M (complex), fused h update epilogue ----
// 32 rows x 256 cols per block; 256 threads; thread = 8 rows x 4 cols.
__global__ __launch_bounds__(256, 2) void main_gemm_kernel(
    const float* __restrict__ x_re, const float* __restrict__ x_im,
    const float* __restrict__ h_re, const float* __restrict__ h_im,
    const float* __restrict__ ws, float* __restrict__ out, int cplx){
  __shared__ float2 xs[BM][KB];
  const int tid = threadIdx.x;
  const int cg = tid & 63;      // column group -> cols cg*4 .. +3
  const int rg = tid >> 6;      // row group    -> rows rg*8 .. +7
  const int row0 = blockIdx.x * BM;
  const int b = row0 >> 12;     // row / 4096 (SPATIAL); 4096 % BM == 0
  const float4* M4 = (const float4*)(ws + WS_M);

  float accr[8][4]; float acci[8][4];
  #pragma unroll
  for (int r = 0; r < 8; ++r)
    #pragma unroll
    for (int c = 0; c < 4; ++c){ accr[r][c] = 0.f; acci[r][c] = 0.f; }

  for (int kk = 0; kk < D; kk += KB){
    __syncthreads();
    #pragma unroll
    for (int i = 0; i < 2; ++i){
      int it = tid + i*256;
      int r = it >> 4, s = it & 15;
      const float4* xr4 = (const float4*)(x_re + (row0 + r)*D + kk);
      const float4* xi4 = (const float4*)(x_im + (row0 + r)*D + kk);
      float4 a = xr4[s], bb = xi4[s];
      float4* dst = (float4*)&xs[r][s*4];
      dst[0] = make_float4(a.x, bb.x, a.y, bb.y);
      dst[1] = make_float4(a.z, bb.z, a.w, bb.w);
    }
    __syncthreads();
    #pragma unroll 4
    for (int k = 0; k < KB; ++k){
      float4 m0 = M4[(kk + k)*128 + cg*2];
      float4 m1 = M4[(kk + k)*128 + cg*2 + 1];
      #pragma unroll
      for (int r = 0; r < 8; ++r){
        float2 xv = xs[rg*8 + r][k];
        accr[r][0] += xv.x*m0.x - xv.y*m0.y;  acci[r][0] += xv.x*m0.y + xv.y*m0.x;
        accr[r][1] += xv.x*m0.z - xv.y*m0.w;  acci[r][1] += xv.x*m0.w + xv.y*m0.z;
        accr[r][2] += xv.x*m1.x - xv.y*m1.y;  acci[r][2] += xv.x*m1.y + xv.y*m1.x;
        accr[r][3] += xv.x*m1.z - xv.y*m1.w;  acci[r][3] += xv.x*m1.w + xv.y*m1.z;
      }
    }
  }

  // epilogue: h_next = h*od + x_tilde*C1 + C0  (real part always; imag only if cplx)
  const int c0 = cg*4;
  const float2* odp = (const float2*)(ws + WS_OD);
  const float2* C1p = (const float2*)(ws + WS_C1) + b*D;
  const float2* C0p = (const float2*)(ws + WS_C0) + b*D;
  float2 od[4], c1[4], cc0[4];
  #pragma unroll
  for (int c = 0; c < 4; ++c){ od[c] = odp[c0+c]; c1[c] = C1p[c0+c]; cc0[c] = C0p[c0+c]; }
  #pragma unroll
  for (int r = 0; r < 8; ++r){
    int row = row0 + rg*8 + r;
    float4 hr = *(const float4*)(h_re + row*D + c0);
    float4 hi = *(const float4*)(h_im + row*D + c0);
    float hrv[4] = {hr.x, hr.y, hr.z, hr.w};
    float hiv[4] = {hi.x, hi.y, hi.z, hi.w};
    float ore[4], oim[4];
    #pragma unroll
    for (int c = 0; c < 4; ++c){
      float xr = accr[r][c], xi = acci[r][c];
      ore[c] = hrv[c]*od[c].x - hiv[c]*od[c].y + xr*c1[c].x - xi*c1[c].y + cc0[c].x;
      oim[c] = hrv[c]*od[c].y + hiv[c]*od[c].x + xr*c1[c].y + xi*c1[c].x + cc0[c].y;
    }
    if (cplx){
      float4* o4 = (float4*)(out + (row*D + c0)*2);
      o4[0] = make_float4(ore[0], oim[0], ore[1], oim[1]);
      o4[1] = make_float4(ore[2], oim[2], ore[3], oim[3]);
    } else {
      *(float4*)(out + row*D + c0) = make_float4(ore[0], ore[1], ore[2], ore[3]);
    }
  }
}

extern "C" void kernel_launch(void* const* d_in, const int* in_sizes, int n_in,
                              void* d_out, int out_size, void* d_ws, size_t ws_size,
                              hipStream_t stream){
  const float* h_re    = (const float*)d_in[0];
  const float* h_im    = (const float*)d_in[1];
  const float* x_re    = (const float*)d_in[2];
  const float* x_im    = (const float*)d_in[3];
  const float* xg_re   = (const float*)d_in[4];
  const float* xg_im   = (const float*)d_in[5];
  const float* flux_re = (const float*)d_in[6];
  const float* flux_im = (const float*)d_in[7];
  const float* U_re    = (const float*)d_in[8];
  const float* U_im    = (const float*)d_in[9];
  const float* dft_w   = (const float*)d_in[10];
  const float* decay_re= (const float*)d_in[11];
  const float* decay_im= (const float*)d_in[12];
  const float* Wm      = (const float*)d_in[13];
  const float* bm      = (const float*)d_in[14];
  const float* Wp      = (const float*)d_in[15];
  const float* bp      = (const float*)d_in[16];
  const float* Wg      = (const float*)d_in[17];
  const float* bg      = (const float*)d_in[18];
  const float* lam_re  = (const float*)d_in[19];
  const float* lam_im  = (const float*)d_in[20];
  const int*   dt      = (const int*)d_in[21];
  float* ws  = (float*)d_ws;
  float* out = (float*)d_out;

  // out_size tells us the harness's complex flattening:
  //   real-parts-only: TBROWS*D + BATCH*D      = 8,390,656 floats
  //   interleaved c64: 2*(TBROWS*D + BATCH*D)  = 16,781,312 floats
  const int cplx = (out_size >= 2*TBROWS*D) ? 1 : 0;
  float* out_flux = out + (size_t)TBROWS*D*(cplx ? 2 : 1);

  prep_batch_kernel<<<BATCH, 768, 0, stream>>>(xg_re, xg_im, flux_re, flux_im, Wm, bm,
                                               decay_re, decay_im, Wp, bp, Wg, bg,
                                               lam_re, lam_im, dt, ws, out_flux, cplx);
  prep_M_kernel<<<D, D, 0, stream>>>(U_re, U_im, dft_w, ws);
  main_gemm_kernel<<<TBROWS/BM, 256, 0, stream>>>(x_re, x_im, h_re, h_im, ws, out, cplx);
}

// Round 5
// 339.428 us; speedup vs baseline: 1.6288x; 1.6288x over previous
//
#include <hip/hip_runtime.h>
#include <math.h>

#define D 256
#define TBROWS 32768
#define BATCH 8

typedef __attribute__((ext_vector_type(4)))  float f32x4;
typedef __attribute__((ext_vector_type(16))) float f32x16;
typedef __attribute__((ext_vector_type(8)))  short short8v;
typedef __attribute__((ext_vector_type(4)))  short short4v;

// ws float-offsets (total ~1.06 MB; ws re-poisoned each call -> all rewritten per launch)
#define WS_OD   0        // op_decay[256] float2          -> 512 f
#define WS_C1   512      // C1[8][256] float2 (gate*of)   -> 4096 f
#define WS_C0   4608     // C0[8][256] float2             -> 4096 f
#define WS_BHI  8704     // B'' hi frags: 262144 ushort   -> 131072 f
#define WS_BLO  139776   // B'' lo frags: 262144 ushort   -> 131072 f

__device__ __forceinline__ float sigmoidf_(float x){ return 1.0f/(1.0f+expf(-x)); }
// bf16 RNE convert without __hip_bfloat16 ABI dependencies
__device__ __forceinline__ unsigned short f2bf(float f){
  unsigned int u = __float_as_uint(f);
  unsigned int r = (u + 0x7FFFu + ((u>>16)&1u)) >> 16;
  return (unsigned short)r;
}
__device__ __forceinline__ float bf2f(unsigned short h){
  return __uint_as_float(((unsigned int)h)<<16);
}

// ---- prep_batch: flux update + proj/gate + per-(b,d) epilogue coefficients ----
__global__ void prep_batch_kernel(const float* __restrict__ xg_re, const float* __restrict__ xg_im,
                                  const float* __restrict__ flux_re, const float* __restrict__ flux_im,
                                  const float* __restrict__ Wm, const float* __restrict__ bm,
                                  const float* __restrict__ decay_re, const float* __restrict__ decay_im,
                                  const float* __restrict__ Wp, const float* __restrict__ bp,
                                  const float* __restrict__ Wg, const float* __restrict__ bg,
                                  const float* __restrict__ lam_re, const float* __restrict__ lam_im,
                                  const int* __restrict__ dt_p,
                                  float* __restrict__ ws, float* __restrict__ out_flux, int cplx){
  __shared__ float vin[512];    // xg_cat, then s_cat
  __shared__ float mid[768];    // x_in, then {proj, gate_pre}
  const int b = blockIdx.x, j = threadIdx.x;
  if (j < 512) vin[j] = (j < D) ? xg_re[b*D + j] : xg_im[b*D + (j - D)];
  __syncthreads();
  if (j < 512){   // x_in = xg_cat @ Wm^T + bm
    const float4* row4 = (const float4*)(Wm + j*512);
    const float4* x4p  = (const float4*)vin;
    float acc = 0.f;
    #pragma unroll 8
    for (int k = 0; k < 128; ++k){
      float4 w4 = row4[k]; float4 x4 = x4p[k];
      acc += w4.x*x4.x + w4.y*x4.y + w4.z*x4.z + w4.w*x4.w;
    }
    mid[j] = acc + bm[j];
  }
  __syncthreads();
  if (j < D){     // flux_next = flux*fdecay + update
    float ur = mid[j], ui = mid[D + j];
    float fdr = sigmoidf_(decay_re[j]);
    float fdi = decay_im[j];
    float fr = flux_re[b*D + j], fi = flux_im[b*D + j];
    float nr = fr*fdr - fi*fdi + ur;
    float ni = fr*fdi + fi*fdr + ui;
    vin[j]     = nr;
    vin[D + j] = ni;
    if (cplx){ out_flux[(b*D + j)*2] = nr; out_flux[(b*D + j)*2 + 1] = ni; }
    else     { out_flux[b*D + j] = nr; }
  }
  __syncthreads();
  {               // proj (j<512) / gate_pre (j>=512)
    const float* rowp = (j < 512) ? (Wp + j*512) : (Wg + (j - 512)*512);
    float bias = (j < 512) ? bp[j] : bg[j - 512];
    const float4* row4 = (const float4*)rowp;
    const float4* x4p  = (const float4*)vin;
    float acc = 0.f;
    #pragma unroll 8
    for (int k = 0; k < 128; ++k){
      float4 w4 = row4[k]; float4 x4 = x4p[k];
      acc += w4.x*x4.x + w4.y*x4.y + w4.z*x4.z + w4.w*x4.w;
    }
    mid[j] = acc + bias;
  }
  __syncthreads();
  if (j < D){     // epilogue coefficients
    float sr = mid[j], si = mid[D + j];
    float g = sigmoidf_(mid[512 + j]);
    g = fminf(fmaxf(g, 0.01f), 0.99f);
    float lrb = fminf(fmaxf(lam_re[j], -0.3f), 0.3f);
    float li  = lam_im[j];
    float dtr = (float)dt_p[0];           // / DT_REF (=1.0)
    float er  = expf(lrb * dtr);
    float ang = li * dtr;
    float odr = er * cosf(ang), odi = er * sinf(ang);
    float sarg = lrb + 1e-12f;
    float sgn = (sarg > 0.f) ? 1.f : ((sarg < 0.f) ? -1.f : 0.f);
    float lrs = lrb + 1e-8f * sgn;
    float nr = odr - 1.f, ni = odi;
    float den = lrs*lrs + li*li;
    float ofr = (nr*lrs + ni*li) / den;
    float ofi = (ni*lrs - nr*li) / den;
    ws[WS_C1 + (b*D + j)*2]     = g * ofr;
    ws[WS_C1 + (b*D + j)*2 + 1] = g * ofi;
    float s1r = sr*(1.f - g), s1i = si*(1.f - g);
    ws[WS_C0 + (b*D + j)*2]     = s1r*ofr - s1i*ofi;
    ws[WS_C0 + (b*D + j)*2 + 1] = s1r*ofi + s1i*ofr;
    if (b == 0){
      ws[WS_OD + j*2]     = odr;
      ws[WS_OD + j*2 + 1] = odi;
    }
  }
}

// ---- prep_B: B''[512][512] (hi/lo bf16) in MFMA fragment order ----
// B''[k'][jj]: jj=2j+part; k'<256 -> xr-row k'; k'>=256 -> xi-row (k'-256)
//   part0 (re col j): {Mr[k][j], -Mi[k][j]};  part1 (im col j): {Mi[k][j], Mr[k][j]}
// frag storage: off = ((s*16+ct)*64 + lane)*8 + j8, s=k'>>4, ct=jj>>5,
//   lane = ((k'&15)>>3)*32 + (jj&31), j8 = k'&7   (A/B layout: k = 8*(lane>>5)+j8)
__global__ void prep_B_kernel(const float* __restrict__ U_re, const float* __restrict__ U_im,
                              const float* __restrict__ dft_w, float* __restrict__ ws){
  const int kp = blockIdx.x;     // k' 0..511
  const int jj = threadIdx.x;    // 0..511
  const int k  = kp & 255, half = kp >> 8;
  const int j  = jj >> 1,  part = jj & 1;
  float w = sigmoidf_(dft_w[0]);
  const float c = -6.283185307179586f;
  float t1 = c * (float)j;                 // same op order as reference dft
  float ph = (t1 * (float)k) / 256.0f;
  float dre = cosf(ph) * 0.0625f;
  float dim = sinf(ph) * 0.0625f;
  float mr = (1.f - w)*U_re[k*D + j] + w*dre;
  float mi = (1.f - w)*U_im[k*D + j] + w*dim;
  float V = part ? (half ? mr : mi) : (half ? -mi : mr);
  unsigned short hi = f2bf(V);
  unsigned short lo = f2bf(V - bf2f(hi));
  int s = kp >> 4, rb = kp & 15;
  int hi5 = rb >> 3, j8 = rb & 7;
  int ct = jj >> 5, lane = hi5*32 + (jj & 31);
  size_t off = ((size_t)(s*16 + ct)*64 + lane)*8 + j8;
  ((unsigned short*)(ws + WS_BHI))[off] = hi;
  ((unsigned short*)(ws + WS_BLO))[off] = lo;
}

// ---- main: C'[32768][512] = A'@B'' via 3-product bf16-split MFMA, fused h-epilogue ----
// 512 blocks x 1024 threads (16 waves). Block = 64 rows x all 512 cols.
// Wave ct = tid>>6 owns col-tile ct (32 jj-cols); 2 row-tiles (rt=0,1) per wave.
__global__ __launch_bounds__(1024) void main_mfma_kernel(
    const float* __restrict__ x_re, const float* __restrict__ x_im,
    const float* __restrict__ h_re, const float* __restrict__ h_im,
    const float* __restrict__ ws, float* __restrict__ out, int cplx){
  __shared__ short Ahi[4096];   // frag-order A chunk: [(sl*2+rt)*64 + lane]*8 + j8
  __shared__ short Alo[4096];
  const int tid  = threadIdx.x;
  const int lane = tid & 63;
  const int ct   = tid >> 6;          // 0..15
  const int row0 = blockIdx.x * 64;
  const int b    = row0 >> 12;        // 4096 rows per batch; 64 | 4096
  const unsigned short* Bh0 = (const unsigned short*)(ws + WS_BHI);
  const unsigned short* Bl0 = (const unsigned short*)(ws + WS_BLO);

  f32x16 acc0 = {}; f32x16 acc1 = {};

  // staging map: thread -> (row, 4 k-values); coalesced f32x4 global read
  const int srow = tid >> 4, sseg = tid & 15;      // row 0..63, seg 0..15 (k = seg*4..+3)
  const int ssl  = sseg >> 2;                      // K-step within chunk
  const int sk16 = (sseg & 3) * 4;                 // k within step: 0,4,8,12
  const int soff = ((((ssl*2) + (srow>>5))*64) + (sk16>>3)*32 + (srow&31))*8 + (sk16&7);

  for (int c = 0; c < 8; ++c){
    __syncthreads();
    {
      const float* src = (c < 4) ? x_re : x_im;
      const int koff = (c & 3)*64;
      f32x4 v = *(const f32x4*)(src + (size_t)(row0 + srow)*256 + koff + sseg*4);
      short4v hv, lv;
      #pragma unroll
      for (int q = 0; q < 4; ++q){
        float f = v[q];
        unsigned short hb = f2bf(f);
        hv[q] = (short)hb;
        lv[q] = (short)f2bf(f - bf2f(hb));
      }
      *(short4v*)&Ahi[soff] = hv;
      *(short4v*)&Alo[soff] = lv;
    }
    __syncthreads();
    #pragma unroll
    for (int sl = 0; sl < 4; ++sl){
      short8v ah0 = *(const short8v*)&Ahi[((sl*2+0)*64 + lane)*8];
      short8v al0 = *(const short8v*)&Alo[((sl*2+0)*64 + lane)*8];
      short8v ah1 = *(const short8v*)&Ahi[((sl*2+1)*64 + lane)*8];
      short8v al1 = *(const short8v*)&Alo[((sl*2+1)*64 + lane)*8];
      const size_t boff = ((size_t)((c*4+sl)*16 + ct)*64 + lane)*8;
      short8v bh = *(const short8v*)(Bh0 + boff);
      short8v bl = *(const short8v*)(Bl0 + boff);
      acc0 = __builtin_amdgcn_mfma_f32_32x32x16_bf16(ah0, bh, acc0, 0,0,0);
      acc1 = __builtin_amdgcn_mfma_f32_32x32x16_bf16(ah1, bh, acc1, 0,0,0);
      acc0 = __builtin_amdgcn_mfma_f32_32x32x16_bf16(al0, bh, acc0, 0,0,0);
      acc1 = __builtin_amdgcn_mfma_f32_32x32x16_bf16(al1, bh, acc1, 0,0,0);
      acc0 = __builtin_amdgcn_mfma_f32_32x32x16_bf16(ah0, bl, acc0, 0,0,0);
      acc1 = __builtin_amdgcn_mfma_f32_32x32x16_bf16(ah1, bl, acc1, 0,0,0);
    }
  }

  // epilogue: lane-pair (re,im) combine + h update
  const int j = ct*16 + ((lane & 31) >> 1);
  const int part = lane & 1;
  const float odr = ws[WS_OD + j*2],           odi = ws[WS_OD + j*2 + 1];
  const float c1r = ws[WS_C1 + (b*D + j)*2],   c1i = ws[WS_C1 + (b*D + j)*2 + 1];
  const float c0r = ws[WS_C0 + (b*D + j)*2],   c0i = ws[WS_C0 + (b*D + j)*2 + 1];
  #pragma unroll
  for (int rt = 0; rt < 2; ++rt){
    #pragma unroll
    for (int r = 0; r < 16; ++r){
      float val = (rt == 0) ? acc0[r] : acc1[r];
      float other = __shfl_xor(val, 1);
      float xr = part ? other : val;
      float xi = part ? val   : other;
      int row = row0 + rt*32 + 4*(lane>>5) + (r & 3) + 8*(r >> 2);
      float hr = h_re[(size_t)row*256 + j];
      float hi = h_im[(size_t)row*256 + j];
      float ore = hr*odr - hi*odi + xr*c1r - xi*c1i + c0r;
      float oim = hr*odi + hi*odr + xr*c1i + xi*c1r + c0i;
      if (cplx){
        out[((size_t)row*256 + j)*2 + part] = part ? oim : ore;
      } else if (!part){
        out[(size_t)row*256 + j] = ore;
      }
    }
  }
}

extern "C" void kernel_launch(void* const* d_in, const int* in_sizes, int n_in,
                              void* d_out, int out_size, void* d_ws, size_t ws_size,
                              hipStream_t stream){
  const float* h_re    = (const float*)d_in[0];
  const float* h_im    = (const float*)d_in[1];
  const float* x_re    = (const float*)d_in[2];
  const float* x_im    = (const float*)d_in[3];
  const float* xg_re   = (const float*)d_in[4];
  const float* xg_im   = (const float*)d_in[5];
  const float* flux_re = (const float*)d_in[6];
  const float* flux_im = (const float*)d_in[7];
  const float* U_re    = (const float*)d_in[8];
  const float* U_im    = (const float*)d_in[9];
  const float* dft_w   = (const float*)d_in[10];
  const float* decay_re= (const float*)d_in[11];
  const float* decay_im= (const float*)d_in[12];
  const float* Wm      = (const float*)d_in[13];
  const float* bm      = (const float*)d_in[14];
  const float* Wp      = (const float*)d_in[15];
  const float* bp      = (const float*)d_in[16];
  const float* Wg      = (const float*)d_in[17];
  const float* bg      = (const float*)d_in[18];
  const float* lam_re  = (const float*)d_in[19];
  const float* lam_im  = (const float*)d_in[20];
  const int*   dt      = (const int*)d_in[21];
  float* ws  = (float*)d_ws;
  float* out = (float*)d_out;

  const int cplx = (out_size >= 2*TBROWS*D) ? 1 : 0;
  float* out_flux = out + (size_t)TBROWS*D*(cplx ? 2 : 1);

  prep_batch_kernel<<<BATCH, 768, 0, stream>>>(xg_re, xg_im, flux_re, flux_im, Wm, bm,
                                               decay_re, decay_im, Wp, bp, Wg, bg,
                                               lam_re, lam_im, dt, ws, out_flux, cplx);
  prep_B_kernel<<<512, 512, 0, stream>>>(U_re, U_im, dft_w, ws);
  main_mfma_kernel<<<TBROWS/64, 1024, 0, stream>>>(x_re, x_im, h_re, h_im, ws, out, cplx);
}